// Round 9
// baseline (94.111 us; speedup 1.0000x reference)
//
#include <hip/hip_runtime.h>
#include <math.h>

#define B_ 8
#define BIGF 3.4e38f

// ws layout (16-B aligned base):
//   packT  : B_*N float4 {x,y,z,|t|^2}
//   packS  : B_*M float4 {x,y,z,|s|^2}
//   minarr : B_*N uint rowmin (per-target min d^2, uint-ordered floats)
//            followed by B_*M uint colmin (per-source min d^2)

__global__ __launch_bounds__(256) void pack_kernel(
    const float* __restrict__ tar, const float* __restrict__ src,
    float4* __restrict__ packT, float4* __restrict__ packS,
    unsigned int* __restrict__ minarr, float* __restrict__ outp,
    int N, int M)
{
    const int i = blockIdx.x * 256 + threadIdx.x;
    const int nT = B_ * N, nS = B_ * M;
    if (i < nT) {
        float x = tar[3 * i], y = tar[3 * i + 1], z = tar[3 * i + 2];
        packT[i] = make_float4(x, y, z, fmaf(x, x, fmaf(y, y, z * z)));
    } else if (i < nT + nS) {
        int j = i - nT;
        float x = src[3 * j], y = src[3 * j + 1], z = src[3 * j + 2];
        packS[j] = make_float4(x, y, z, fmaf(x, x, fmaf(y, y, z * z)));
    }
    if (i < nT + nS) minarr[i] = 0x7F800000u;  // +inf
    if (i < 3) outp[i] = 0.f;
}

// Two-pass structure (both dirs via blockIdx.z), QPT=16 so the inner loop is
// VALU-bound not LDS-bound: per j-pair iter, 112 VALU wave-insts (56 CU-cyc)
// vs 2 ds_read_b128 (2048 B ~= 24 CU-cyc at 85 B/cyc) -> 2.3x VALU margin.
// (QPT=8 had 28 cyc VALU vs 24 cyc LDS -> LDS-throughput-bound, ~30 us.)
// CHUNK=64 keeps the grid at 1024 blocks = 4/CU = 16 waves/CU.
// d^2 = |q|^2 + (|p|^2 - 2 q.p); |q|^2 added after the min (monotone).
// Cross-block combine: distributed uint atomicMin (d^2 clamped >= 0).
template <int QPT, int CHUNK>
__global__ __launch_bounds__(256) void minsq_kernel(
    const float4* __restrict__ packT, const float4* __restrict__ packS,
    unsigned int* __restrict__ minarr, int N, int M)
{
    const int z   = blockIdx.z;
    const int dir = (z >= B_) ? 1 : 0;
    const int b   = dir ? (z - B_) : z;
    const float4* __restrict__ qry = dir ? packS : packT;
    const float4* __restrict__ pts = dir ? packT : packS;
    const int K = dir ? M : N;   // query count
    const int L = dir ? N : M;   // reference count
    unsigned int* __restrict__ out =
        minarr + (dir ? (size_t)B_ * N : (size_t)0) + (size_t)b * K;

    const int base = blockIdx.y * CHUNK;
    if (base >= L) return;
    const int cnt = min(CHUNK, L - base);

    __shared__ float4 sp[CHUNK];
    const float4* __restrict__ psrc = pts + (size_t)b * L + base;
    const int t = threadIdx.x;
    for (int i = t; i < cnt; i += 256) sp[i] = psrc[i];
    __syncthreads();

    const int qbase = blockIdx.x * (256 * QPT);
    float qx2[QPT], qy2[QPT], qz2[QPT], qw[QPT], mn[QPT];
#pragma unroll
    for (int k = 0; k < QPT; ++k) {
        int qi = qbase + k * 256 + t;
        if (qi < K) {
            float4 q = qry[(size_t)b * K + qi];
            qx2[k] = -2.f * q.x; qy2[k] = -2.f * q.y; qz2[k] = -2.f * q.z;
            qw[k] = q.w;
        } else {
            qx2[k] = 0.f; qy2[k] = 0.f; qz2[k] = 0.f; qw[k] = 0.f;
        }
        mn[k] = BIGF;
    }

    if (cnt == CHUNK) {
#pragma unroll 2
        for (int j = 0; j < CHUNK; j += 2) {
            float4 p0 = sp[j];
            float4 p1 = sp[j + 1];
#pragma unroll
            for (int k = 0; k < QPT; ++k) {
                float d0 = fmaf(qx2[k], p0.x, fmaf(qy2[k], p0.y,
                           fmaf(qz2[k], p0.z, p0.w)));
                float d1 = fmaf(qx2[k], p1.x, fmaf(qy2[k], p1.y,
                           fmaf(qz2[k], p1.z, p1.w)));
                mn[k] = fminf(mn[k], fminf(d0, d1));   // v_min3_f32
            }
        }
    } else {
        int j = 0;
        for (; j + 1 < cnt; j += 2) {
            float4 p0 = sp[j];
            float4 p1 = sp[j + 1];
#pragma unroll
            for (int k = 0; k < QPT; ++k) {
                float d0 = fmaf(qx2[k], p0.x, fmaf(qy2[k], p0.y,
                           fmaf(qz2[k], p0.z, p0.w)));
                float d1 = fmaf(qx2[k], p1.x, fmaf(qy2[k], p1.y,
                           fmaf(qz2[k], p1.z, p1.w)));
                mn[k] = fminf(mn[k], fminf(d0, d1));
            }
        }
        if (j < cnt) {
            float4 p0 = sp[j];
#pragma unroll
            for (int k = 0; k < QPT; ++k) {
                float d0 = fmaf(qx2[k], p0.x, fmaf(qy2[k], p0.y,
                           fmaf(qz2[k], p0.z, p0.w)));
                mn[k] = fminf(mn[k], d0);
            }
        }
    }

#pragma unroll
    for (int k = 0; k < QPT; ++k) {
        int qi = qbase + k * 256 + t;
        if (qi < K) {
            float d2 = fmaxf(mn[k] + qw[k], 0.f);  // clamp roundoff negatives
            atomicMin(&out[qi], __float_as_uint(d2));
        }
    }
}

// Merged reduce+finalize: 32 blocks stripe-sum sqrt of both regions, then 3
// scaled atomicAdds into d_out (zeroed by pack_kernel).
__global__ __launch_bounds__(256) void reduce_kernel(
    const unsigned int* __restrict__ minarr, float* __restrict__ outp,
    int N, int M)
{
    const int nt = B_ * N, ns = B_ * M;
    const int gid = blockIdx.x * 256 + threadIdx.x;
    const int stride = gridDim.x * 256;
    float s_t = 0.f, s_s = 0.f;
    for (int i = gid; i < nt; i += stride)
        s_t += sqrtf(__uint_as_float(minarr[i]));
    for (int i = gid; i < ns; i += stride)
        s_s += sqrtf(__uint_as_float(minarr[nt + i]));
#pragma unroll
    for (int off = 32; off > 0; off >>= 1) {
        s_t += __shfl_down(s_t, off);
        s_s += __shfl_down(s_s, off);
    }
    __shared__ float rt[4], rs[4];
    const int wid = threadIdx.x >> 6, lid = threadIdx.x & 63;
    if (lid == 0) { rt[wid] = s_t; rs[wid] = s_s; }
    __syncthreads();
    if (threadIdx.x == 0) {
        float ct = (rt[0] + rt[1] + rt[2] + rt[3]) / (float)nt;  // complete
        float ac = (rs[0] + rs[1] + rs[2] + rs[3]) / (float)ns;  // accuracy
        atomicAdd(&outp[0], ac);
        atomicAdd(&outp[1], ct);
        atomicAdd(&outp[2], 0.5f * (ac + ct));
    }
}

extern "C" void kernel_launch(void* const* d_in, const int* in_sizes, int n_in,
                              void* d_out, int out_size, void* d_ws, size_t ws_size,
                              hipStream_t stream) {
    const float* tar = (const float*)d_in[0];
    const float* src = (const float*)d_in[1];
    const int N = in_sizes[0] / (B_ * 3);
    const int M = in_sizes[1] / (B_ * 3);

    float4* packT = (float4*)d_ws;
    float4* packS = packT + (size_t)B_ * N;
    unsigned int* minarr = (unsigned int*)(packS + (size_t)B_ * M);
    float* outp = (float*)d_out;

    pack_kernel<<<dim3((B_ * (N + M) + 255) / 256), dim3(256), 0, stream>>>(
        tar, src, packT, packS, minarr, outp, N, M);

    constexpr int QPT = 16, CHUNK = 64;
    const int KL = (N > M) ? N : M;
    const int gx = (KL + 256 * QPT - 1) / (256 * QPT);   // 1
    const int gy = (KL + CHUNK - 1) / CHUNK;             // 64
    dim3 grid(gx, gy, 2 * B_);                            // 1024 blocks
    minsq_kernel<QPT, CHUNK><<<grid, dim3(256), 0, stream>>>(
        packT, packS, minarr, N, M);

    reduce_kernel<<<dim3(32), dim3(256), 0, stream>>>(minarr, outp, N, M);
}

// Round 10
// 94.001 us; speedup vs baseline: 1.0012x; 1.0012x over previous
//
#include <hip/hip_runtime.h>
#include <math.h>

#define B_ 8
#define BIGF 3.4e38f

// ws layout (16-B aligned base):
//   packT  : B_*N float4 {x,y,z,|t|^2}
//   packS  : B_*M float4 {x,y,z,|s|^2}
//   minarr : B_*N uint rowmin (per-target min d^2, uint-ordered floats)
//            followed by B_*M uint colmin (per-source min d^2)

__global__ __launch_bounds__(256) void pack_kernel(
    const float* __restrict__ tar, const float* __restrict__ src,
    float4* __restrict__ packT, float4* __restrict__ packS,
    unsigned int* __restrict__ minarr, float* __restrict__ outp,
    int N, int M)
{
    const int i = blockIdx.x * 256 + threadIdx.x;
    const int nT = B_ * N, nS = B_ * M;
    if (i < nT) {
        float x = tar[3 * i], y = tar[3 * i + 1], z = tar[3 * i + 2];
        packT[i] = make_float4(x, y, z, fmaf(x, x, fmaf(y, y, z * z)));
    } else if (i < nT + nS) {
        int j = i - nT;
        float x = src[3 * j], y = src[3 * j + 1], z = src[3 * j + 2];
        packS[j] = make_float4(x, y, z, fmaf(x, x, fmaf(y, y, z * z)));
    }
    if (i < nT + nS) minarr[i] = 0x7F800000u;  // +inf
    if (i < 3) outp[i] = 0.f;
}

// NO-LDS inner loop: the ref point pts[j] is wave-uniform (uniform base +
// loop counter), so the compiler scalarizes it to s_load_dwordx4 via the
// scalar cache — issues on the scalar pipe, zero VALU/DS slots, no barrier,
// no staging. (R2-R9 evidence: LDS-staged loop stuck at ~30 us ~ 2.5x the
// VALU floor at every QPT/CHUNK; broadcast ds_read + addressing + waitcnt
// was the hidden cost.)
// Per j: 1 v_mov (p.w -> VGPR) + QPT*(3 fma + 0.5 min3) => 3.75 VALU/pair.
// d^2 = |q|^2 + (|p|^2 - 2 q.p); |q|^2 added after the min (monotone).
// Cross-block combine: distributed uint atomicMin, gy=16 contenders/addr
// (R9 lesson: gy=64 -> 4.2M atomics cost ~10 us; keep atomics ~1M).
template <int QPT, int CHUNK>
__global__ __launch_bounds__(256) void minsq_kernel(
    const float4* __restrict__ packT, const float4* __restrict__ packS,
    unsigned int* __restrict__ minarr, int N, int M)
{
    const int z   = blockIdx.z;
    const int dir = (z >= B_) ? 1 : 0;
    const int b   = dir ? (z - B_) : z;
    const float4* __restrict__ qry = dir ? packS : packT;
    const float4* __restrict__ pts = dir ? packT : packS;
    const int K = dir ? M : N;   // query count
    const int L = dir ? N : M;   // reference count
    unsigned int* __restrict__ out =
        minarr + (dir ? (size_t)B_ * N : (size_t)0) + (size_t)b * K;

    const int base = blockIdx.y * CHUNK;
    if (base >= L) return;
    const int cnt = min(CHUNK, L - base);
    const float4* __restrict__ pr = pts + (size_t)b * L + base;  // uniform

    const int t = threadIdx.x;
    const int qbase = blockIdx.x * (256 * QPT);
    float qx2[QPT], qy2[QPT], qz2[QPT], qw[QPT], mn[QPT];
#pragma unroll
    for (int k = 0; k < QPT; ++k) {
        int qi = qbase + k * 256 + t;
        if (qi < K) {
            float4 q = qry[(size_t)b * K + qi];
            qx2[k] = -2.f * q.x; qy2[k] = -2.f * q.y; qz2[k] = -2.f * q.z;
            qw[k] = q.w;
        } else {
            qx2[k] = 0.f; qy2[k] = 0.f; qz2[k] = 0.f; qw[k] = 0.f;
        }
        mn[k] = BIGF;
    }

    if (cnt == CHUNK) {
#pragma unroll 4
        for (int j = 0; j < CHUNK; j += 2) {
            const float4 p0 = pr[j];         // uniform -> s_load_dwordx4
            const float4 p1 = pr[j + 1];
#pragma unroll
            for (int k = 0; k < QPT; ++k) {
                float d0 = fmaf(qz2[k], p0.z, p0.w);   // s_pz, s_pw -> 1 v_mov/j
                d0 = fmaf(qy2[k], p0.y, d0);
                d0 = fmaf(qx2[k], p0.x, d0);
                float d1 = fmaf(qz2[k], p1.z, p1.w);
                d1 = fmaf(qy2[k], p1.y, d1);
                d1 = fmaf(qx2[k], p1.x, d1);
                mn[k] = fminf(mn[k], fminf(d0, d1));   // v_min3_f32
            }
        }
    } else {
        int j = 0;
        for (; j + 1 < cnt; j += 2) {
            const float4 p0 = pr[j];
            const float4 p1 = pr[j + 1];
#pragma unroll
            for (int k = 0; k < QPT; ++k) {
                float d0 = fmaf(qz2[k], p0.z, p0.w);
                d0 = fmaf(qy2[k], p0.y, d0);
                d0 = fmaf(qx2[k], p0.x, d0);
                float d1 = fmaf(qz2[k], p1.z, p1.w);
                d1 = fmaf(qy2[k], p1.y, d1);
                d1 = fmaf(qx2[k], p1.x, d1);
                mn[k] = fminf(mn[k], fminf(d0, d1));
            }
        }
        if (j < cnt) {
            const float4 p0 = pr[j];
#pragma unroll
            for (int k = 0; k < QPT; ++k) {
                float d0 = fmaf(qz2[k], p0.z, p0.w);
                d0 = fmaf(qy2[k], p0.y, d0);
                d0 = fmaf(qx2[k], p0.x, d0);
                mn[k] = fminf(mn[k], d0);
            }
        }
    }

#pragma unroll
    for (int k = 0; k < QPT; ++k) {
        int qi = qbase + k * 256 + t;
        if (qi < K) {
            float d2 = fmaxf(mn[k] + qw[k], 0.f);  // clamp roundoff negatives
            atomicMin(&out[qi], __float_as_uint(d2));
        }
    }
}

// Merged reduce+finalize: 32 blocks stripe-sum sqrt of both regions, then 3
// scaled atomicAdds into d_out (zeroed by pack_kernel).
__global__ __launch_bounds__(256) void reduce_kernel(
    const unsigned int* __restrict__ minarr, float* __restrict__ outp,
    int N, int M)
{
    const int nt = B_ * N, ns = B_ * M;
    const int gid = blockIdx.x * 256 + threadIdx.x;
    const int stride = gridDim.x * 256;
    float s_t = 0.f, s_s = 0.f;
    for (int i = gid; i < nt; i += stride)
        s_t += sqrtf(__uint_as_float(minarr[i]));
    for (int i = gid; i < ns; i += stride)
        s_s += sqrtf(__uint_as_float(minarr[nt + i]));
#pragma unroll
    for (int off = 32; off > 0; off >>= 1) {
        s_t += __shfl_down(s_t, off);
        s_s += __shfl_down(s_s, off);
    }
    __shared__ float rt[4], rs[4];
    const int wid = threadIdx.x >> 6, lid = threadIdx.x & 63;
    if (lid == 0) { rt[wid] = s_t; rs[wid] = s_s; }
    __syncthreads();
    if (threadIdx.x == 0) {
        float ct = (rt[0] + rt[1] + rt[2] + rt[3]) / (float)nt;  // complete
        float ac = (rs[0] + rs[1] + rs[2] + rs[3]) / (float)ns;  // accuracy
        atomicAdd(&outp[0], ac);
        atomicAdd(&outp[1], ct);
        atomicAdd(&outp[2], 0.5f * (ac + ct));
    }
}

extern "C" void kernel_launch(void* const* d_in, const int* in_sizes, int n_in,
                              void* d_out, int out_size, void* d_ws, size_t ws_size,
                              hipStream_t stream) {
    const float* tar = (const float*)d_in[0];
    const float* src = (const float*)d_in[1];
    const int N = in_sizes[0] / (B_ * 3);
    const int M = in_sizes[1] / (B_ * 3);

    float4* packT = (float4*)d_ws;
    float4* packS = packT + (size_t)B_ * N;
    unsigned int* minarr = (unsigned int*)(packS + (size_t)B_ * M);
    float* outp = (float*)d_out;

    pack_kernel<<<dim3((B_ * (N + M) + 255) / 256), dim3(256), 0, stream>>>(
        tar, src, packT, packS, minarr, outp, N, M);

    constexpr int QPT = 4, CHUNK = 256;
    const int KL = (N > M) ? N : M;
    const int gx = (KL + 256 * QPT - 1) / (256 * QPT);   // 4
    const int gy = (KL + CHUNK - 1) / CHUNK;             // 16
    dim3 grid(gx, gy, 2 * B_);                            // 1024 blocks
    minsq_kernel<QPT, CHUNK><<<grid, dim3(256), 0, stream>>>(
        packT, packS, minarr, N, M);

    reduce_kernel<<<dim3(32), dim3(256), 0, stream>>>(minarr, outp, N, M);
}

// Round 11
// 84.579 us; speedup vs baseline: 1.1127x; 1.1114x over previous
//
#include <hip/hip_runtime.h>
#include <math.h>

#define B_ 8
#define BIGF 3.4e38f

// ws layout (16-B aligned base):
//   packT  : B_*N float4 {x,y,z,|t|^2}
//   packS  : B_*M float4 {x,y,z,|s|^2}
//   minarr : B_*N uint rowmin (per-target min d^2, uint-ordered floats)
//            followed by B_*M uint colmin (per-source min d^2)
// This is the R8 configuration verbatim — measured best (83.5 us).

// Pack points to float4, init min arrays to +inf, zero d_out. One node.
__global__ __launch_bounds__(256) void pack_kernel(
    const float* __restrict__ tar, const float* __restrict__ src,
    float4* __restrict__ packT, float4* __restrict__ packS,
    unsigned int* __restrict__ minarr, float* __restrict__ outp,
    int N, int M)
{
    const int i = blockIdx.x * 256 + threadIdx.x;
    const int nT = B_ * N, nS = B_ * M;
    if (i < nT) {
        float x = tar[3 * i], y = tar[3 * i + 1], z = tar[3 * i + 2];
        packT[i] = make_float4(x, y, z, fmaf(x, x, fmaf(y, y, z * z)));
    } else if (i < nT + nS) {
        int j = i - nT;
        float x = src[3 * j], y = src[3 * j + 1], z = src[3 * j + 2];
        packS[j] = make_float4(x, y, z, fmaf(x, x, fmaf(y, y, z * z)));
    }
    if (i < nT + nS) minarr[i] = 0x7F800000u;  // +inf
    if (i < 3) outp[i] = 0.f;
}

// Two-pass structure (both dirs via blockIdx.z), LDS-staged float4 refs.
// QPT=8, CHUNK=128, grid 2x32x16 = 1024 blocks (4/CU, 16 waves/CU).
// d^2 = |q|^2 + (|p|^2 - 2 q.p); |q|^2 added after the min (monotone).
// Cross-block combine: distributed uint atomicMin (d^2 clamped >= 0 so
// uint order == float order); 2.1M atomics total (proven OK scale).
template <int QPT, int CHUNK>
__global__ __launch_bounds__(256) void minsq_kernel(
    const float4* __restrict__ packT, const float4* __restrict__ packS,
    unsigned int* __restrict__ minarr, int N, int M)
{
    const int z   = blockIdx.z;
    const int dir = (z >= B_) ? 1 : 0;
    const int b   = dir ? (z - B_) : z;
    const float4* __restrict__ qry = dir ? packS : packT;
    const float4* __restrict__ pts = dir ? packT : packS;
    const int K = dir ? M : N;   // query count
    const int L = dir ? N : M;   // reference count
    unsigned int* __restrict__ out =
        minarr + (dir ? (size_t)B_ * N : (size_t)0) + (size_t)b * K;

    const int base = blockIdx.y * CHUNK;
    if (base >= L) return;
    const int cnt = min(CHUNK, L - base);

    __shared__ float4 sp[CHUNK];
    const float4* __restrict__ psrc = pts + (size_t)b * L + base;
    const int t = threadIdx.x;
    for (int i = t; i < cnt; i += 256) sp[i] = psrc[i];
    __syncthreads();

    const int qbase = blockIdx.x * (256 * QPT);
    float qx2[QPT], qy2[QPT], qz2[QPT], qw[QPT], mn[QPT];
#pragma unroll
    for (int k = 0; k < QPT; ++k) {
        int qi = qbase + k * 256 + t;
        if (qi < K) {
            float4 q = qry[(size_t)b * K + qi];
            qx2[k] = -2.f * q.x; qy2[k] = -2.f * q.y; qz2[k] = -2.f * q.z;
            qw[k] = q.w;
        } else {
            qx2[k] = 0.f; qy2[k] = 0.f; qz2[k] = 0.f; qw[k] = 0.f;
        }
        mn[k] = BIGF;
    }

    if (cnt == CHUNK) {
#pragma unroll 4
        for (int j = 0; j < CHUNK; j += 2) {
            float4 p0 = sp[j];
            float4 p1 = sp[j + 1];
#pragma unroll
            for (int k = 0; k < QPT; ++k) {
                float d0 = fmaf(qx2[k], p0.x, fmaf(qy2[k], p0.y,
                           fmaf(qz2[k], p0.z, p0.w)));
                float d1 = fmaf(qx2[k], p1.x, fmaf(qy2[k], p1.y,
                           fmaf(qz2[k], p1.z, p1.w)));
                mn[k] = fminf(mn[k], fminf(d0, d1));   // v_min3_f32
            }
        }
    } else {
        int j = 0;
        for (; j + 1 < cnt; j += 2) {
            float4 p0 = sp[j];
            float4 p1 = sp[j + 1];
#pragma unroll
            for (int k = 0; k < QPT; ++k) {
                float d0 = fmaf(qx2[k], p0.x, fmaf(qy2[k], p0.y,
                           fmaf(qz2[k], p0.z, p0.w)));
                float d1 = fmaf(qx2[k], p1.x, fmaf(qy2[k], p1.y,
                           fmaf(qz2[k], p1.z, p1.w)));
                mn[k] = fminf(mn[k], fminf(d0, d1));
            }
        }
        if (j < cnt) {
            float4 p0 = sp[j];
#pragma unroll
            for (int k = 0; k < QPT; ++k) {
                float d0 = fmaf(qx2[k], p0.x, fmaf(qy2[k], p0.y,
                           fmaf(qz2[k], p0.z, p0.w)));
                mn[k] = fminf(mn[k], d0);
            }
        }
    }

#pragma unroll
    for (int k = 0; k < QPT; ++k) {
        int qi = qbase + k * 256 + t;
        if (qi < K) {
            float d2 = fmaxf(mn[k] + qw[k], 0.f);  // clamp roundoff negatives
            atomicMin(&out[qi], __float_as_uint(d2));
        }
    }
}

// Merged reduce+finalize: 32 blocks stripe-sum sqrt of both regions, then 3
// scaled atomicAdds into d_out (zeroed by pack_kernel). 96 same-line atomics.
__global__ __launch_bounds__(256) void reduce_kernel(
    const unsigned int* __restrict__ minarr, float* __restrict__ outp,
    int N, int M)
{
    const int nt = B_ * N, ns = B_ * M;
    const int gid = blockIdx.x * 256 + threadIdx.x;
    const int stride = gridDim.x * 256;
    float s_t = 0.f, s_s = 0.f;
    for (int i = gid; i < nt; i += stride)
        s_t += sqrtf(__uint_as_float(minarr[i]));
    for (int i = gid; i < ns; i += stride)
        s_s += sqrtf(__uint_as_float(minarr[nt + i]));
#pragma unroll
    for (int off = 32; off > 0; off >>= 1) {
        s_t += __shfl_down(s_t, off);
        s_s += __shfl_down(s_s, off);
    }
    __shared__ float rt[4], rs[4];
    const int wid = threadIdx.x >> 6, lid = threadIdx.x & 63;
    if (lid == 0) { rt[wid] = s_t; rs[wid] = s_s; }
    __syncthreads();
    if (threadIdx.x == 0) {
        float ct = (rt[0] + rt[1] + rt[2] + rt[3]) / (float)nt;  // complete
        float ac = (rs[0] + rs[1] + rs[2] + rs[3]) / (float)ns;  // accuracy
        atomicAdd(&outp[0], ac);
        atomicAdd(&outp[1], ct);
        atomicAdd(&outp[2], 0.5f * (ac + ct));
    }
}

extern "C" void kernel_launch(void* const* d_in, const int* in_sizes, int n_in,
                              void* d_out, int out_size, void* d_ws, size_t ws_size,
                              hipStream_t stream) {
    const float* tar = (const float*)d_in[0];
    const float* src = (const float*)d_in[1];
    const int N = in_sizes[0] / (B_ * 3);
    const int M = in_sizes[1] / (B_ * 3);

    float4* packT = (float4*)d_ws;
    float4* packS = packT + (size_t)B_ * N;
    unsigned int* minarr = (unsigned int*)(packS + (size_t)B_ * M);
    float* outp = (float*)d_out;

    pack_kernel<<<dim3((B_ * (N + M) + 255) / 256), dim3(256), 0, stream>>>(
        tar, src, packT, packS, minarr, outp, N, M);

    constexpr int QPT = 8, CHUNK = 128;
    const int KL = (N > M) ? N : M;
    const int gx = (KL + 256 * QPT - 1) / (256 * QPT);   // 2
    const int gy = (KL + CHUNK - 1) / CHUNK;             // 32
    dim3 grid(gx, gy, 2 * B_);                            // 1024 blocks
    minsq_kernel<QPT, CHUNK><<<grid, dim3(256), 0, stream>>>(
        packT, packS, minarr, N, M);

    reduce_kernel<<<dim3(32), dim3(256), 0, stream>>>(minarr, outp, N, M);
}